// Round 1
// baseline (515.396 us; speedup 1.0000x reference)
//
#include <hip/hip_runtime.h>
#include <stdint.h>

#define T_STEPS 512
#define D_INP   32
#define CHUNK   8
#define NCHUNK  (T_STEPS / CHUNK)

typedef float f4 __attribute__((ext_vector_type(4)));

typedef const uint32_t __attribute__((address_space(1)))* gas1_t;
typedef uint32_t __attribute__((address_space(3)))* las3_t;

template <int K>
__device__ __forceinline__ float qbcast(float v) {
  // broadcast lane (quad_base + K) to all 4 lanes of each quad (VALU pipe)
  return __int_as_float(
      __builtin_amdgcn_mov_dpp(__float_as_int(v), K * 85, 0xF, 0xF, true));
}

__device__ __forceinline__ float frcp(float v) { return __builtin_amdgcn_rcpf(v); }

extern "C" __global__ void __launch_bounds__(256)
lstm2_fused(const float* __restrict__ x,
            const float* __restrict__ Wih0, const float* __restrict__ Whh0,
            const float* __restrict__ bih0, const float* __restrict__ bhh0,
            const float* __restrict__ Wih1, const float* __restrict__ Whh1,
            const float* __restrict__ bih1, const float* __restrict__ bhh1,
            const float* __restrict__ fc1w, const float* __restrict__ fc1b,
            const float* __restrict__ fc2w, const float* __restrict__ fc2b,
            float* __restrict__ out)
{
  __shared__ __align__(16) float lx[4][2][CHUNK * D_INP]; // 8KB: x staging, dbuf
  __shared__ __align__(16) float lh0[4][80];              // [0:16) h0, [16:80) dump
  __shared__ __align__(16) float lh1[4][80];

  const int tid  = threadIdx.x;
  const int w    = tid >> 6;
  const int lane = tid & 63;
  const int b    = (blockIdx.x << 2) + w;

  const int k   = lane & 3;      // gate type: 0=i 1=f 2=g(tanh) 3=o
  const int u   = lane >> 2;     // hidden unit 0..15
  const int row = k * 16 + u;    // weight row in the 64-gate matrices

  // ---- per-lane weights in VGPRs ----
  float wi0[32], wh0[16], wi1[16], wh1[16];
  {
    const f4* p = (const f4*)(Wih0 + row * 32);
#pragma unroll
    for (int q = 0; q < 8; ++q) {
      f4 v = p[q];
#pragma unroll
      for (int r = 0; r < 4; ++r) wi0[4 * q + r] = v[r];
    }
    const f4* p0 = (const f4*)(Whh0 + row * 16);
    const f4* p1 = (const f4*)(Wih1 + row * 16);
    const f4* p2 = (const f4*)(Whh1 + row * 16);
#pragma unroll
    for (int q = 0; q < 4; ++q) {
      f4 a = p0[q], bq = p1[q], cq = p2[q];
#pragma unroll
      for (int r = 0; r < 4; ++r) {
        wh0[4 * q + r] = a[r];
        wi1[4 * q + r] = bq[r];
        wh1[4 * q + r] = cq[r];
      }
    }
  }
  const float bs0 = bih0[row] + bhh0[row];
  const float bs1 = bih1[row] + bhh1[row];

  // activation constants: sigmoid for i,f,o ; tanh = 2*sigmoid(2z)-1 for g
  const float pre = (k == 2) ? -2.0f : -1.0f;
  const float mA  = (k == 2) ?  2.0f :  1.0f;
  const float aA  = (k == 2) ? -1.0f :  0.0f;

  // branchless compact h write: k==0 lanes land in [0:16), others in dump zone
  const int slot = (k == 0) ? u : (16 + lane);
  float* h0slot = &lh0[w][slot];
  float* h1slot = &lh1[w][slot];

  float c0 = 0.f, c1 = 0.f;
  float h0bc[16];
#pragma unroll
  for (int j = 0; j < 16; ++j) h0bc[j] = 0.f;
  if (lane < 16) lh1[w][lane] = 0.f;  // h1[t=-1] = 0 (read before first write)

  const float* xg = x + (size_t)b * (T_STEPS * D_INP);

  // stage chunk 0 (1KB contiguous: 64 lanes x 16B)
  {
    const float* src = xg + lane * 4;
    __builtin_amdgcn_global_load_lds((gas1_t)(const void*)src,
                                     (las3_t)(void*)&lx[w][0][0], 16, 0, 0);
  }

#pragma unroll 1
  for (int c = 0; c < NCHUNK; ++c) {
    asm volatile("s_waitcnt vmcnt(0)" ::: "memory");
    if (c + 1 < NCHUNK) {
      const float* src = xg + (c + 1) * (CHUNK * D_INP) + lane * 4;
      __builtin_amdgcn_global_load_lds((gas1_t)(const void*)src,
                                       (las3_t)(void*)&lx[w][(c + 1) & 1][0],
                                       16, 0, 0);
    }
    const float* xp = &lx[w][c & 1][0];
#pragma unroll
    for (int tt = 0; tt < CHUNK; ++tt) {
      const float* xq = xp + tt * D_INP;
      // ======== layer 0 ========
      float s0 = bs0, s1 = 0.f, s2 = 0.f, s3 = 0.f;
#pragma unroll
      for (int q = 0; q < 8; ++q) {
        f4 v = *(const f4*)(xq + 4 * q);   // ds_read_b128 broadcast
        s0 = fmaf(wi0[4 * q + 0], v[0], s0);
        s1 = fmaf(wi0[4 * q + 1], v[1], s1);
        s2 = fmaf(wi0[4 * q + 2], v[2], s2);
        s3 = fmaf(wi0[4 * q + 3], v[3], s3);
      }
#pragma unroll
      for (int q = 0; q < 4; ++q) {
        s0 = fmaf(wh0[4 * q + 0], h0bc[4 * q + 0], s0);
        s1 = fmaf(wh0[4 * q + 1], h0bc[4 * q + 1], s1);
        s2 = fmaf(wh0[4 * q + 2], h0bc[4 * q + 2], s2);
        s3 = fmaf(wh0[4 * q + 3], h0bc[4 * q + 3], s3);
      }
      float gs = (s0 + s1) + (s2 + s3);
      float av = fmaf(frcp(1.f + __expf(pre * gs)), mA, aA);
      float iv = qbcast<0>(av), fv = qbcast<1>(av);
      float gv = qbcast<2>(av), ov = qbcast<3>(av);
      c0 = fmaf(fv, c0, iv * gv);
      float th = fmaf(2.f, frcp(1.f + __expf(-2.f * c0)), -1.f);
      float h0n = ov * th;
      *h0slot = h0n;                        // compact write of h0[t]
#pragma unroll
      for (int q = 0; q < 4; ++q) {         // broadcast h0[t]; reused for Whh0(t+1)
        f4 hv = *(const f4*)(&lh0[w][4 * q]);
#pragma unroll
        for (int r = 0; r < 4; ++r) h0bc[4 * q + r] = hv[r];
      }
      // ======== layer 1 ========
      float t0 = bs1, t1 = 0.f, t2 = 0.f, t3 = 0.f;
#pragma unroll
      for (int q = 0; q < 4; ++q) {
        t0 = fmaf(wi1[4 * q + 0], h0bc[4 * q + 0], t0);
        t1 = fmaf(wi1[4 * q + 1], h0bc[4 * q + 1], t1);
        t2 = fmaf(wi1[4 * q + 2], h0bc[4 * q + 2], t2);
        t3 = fmaf(wi1[4 * q + 3], h0bc[4 * q + 3], t3);
      }
#pragma unroll
      for (int q = 0; q < 4; ++q) {         // h1[t-1] broadcast (read old, then write)
        f4 hv = *(const f4*)(&lh1[w][4 * q]);
        t0 = fmaf(wh1[4 * q + 0], hv[0], t0);
        t1 = fmaf(wh1[4 * q + 1], hv[1], t1);
        t2 = fmaf(wh1[4 * q + 2], hv[2], t2);
        t3 = fmaf(wh1[4 * q + 3], hv[3], t3);
      }
      float gs1 = (t0 + t1) + (t2 + t3);
      float av1 = fmaf(frcp(1.f + __expf(pre * gs1)), mA, aA);
      float iv1 = qbcast<0>(av1), fv1 = qbcast<1>(av1);
      float gv1 = qbcast<2>(av1), ov1 = qbcast<3>(av1);
      c1 = fmaf(fv1, c1, iv1 * gv1);
      float th1 = fmaf(2.f, frcp(1.f + __expf(-2.f * c1)), -1.f);
      float h1n = ov1 * th1;
      *h1slot = h1n;                        // h1[t] for next step
    }
  }

  // ======== head: y = relu(h1_T @ fc1^T + b1) @ fc2^T + b2 ========
  float h1f[16];
#pragma unroll
  for (int q = 0; q < 4; ++q) {
    f4 hv = *(const f4*)(&lh1[w][4 * q]);
#pragma unroll
    for (int r = 0; r < 4; ++r) h1f[4 * q + r] = hv[r];
  }
  float rr = 0.f;
  if (lane < 8) {
    float acc = fc1b[lane];
#pragma unroll
    for (int j = 0; j < 16; ++j) acc = fmaf(fc1w[lane * 16 + j], h1f[j], acc);
    rr = fmaxf(acc, 0.f) * fc2w[lane];
  }
  rr += __shfl_xor(rr, 1, 64);
  rr += __shfl_xor(rr, 2, 64);
  rr += __shfl_xor(rr, 4, 64);
  if (lane == 0) out[b] = rr + fc2b[0];
}

extern "C" void kernel_launch(void* const* d_in, const int* in_sizes, int n_in,
                              void* d_out, int out_size, void* d_ws, size_t ws_size,
                              hipStream_t stream) {
  (void)in_sizes; (void)n_in; (void)d_ws; (void)ws_size; (void)out_size;
  const float* x    = (const float*)d_in[0];
  const float* Wih0 = (const float*)d_in[1];
  const float* Whh0 = (const float*)d_in[2];
  const float* bih0 = (const float*)d_in[3];
  const float* bhh0 = (const float*)d_in[4];
  const float* Wih1 = (const float*)d_in[5];
  const float* Whh1 = (const float*)d_in[6];
  const float* bih1 = (const float*)d_in[7];
  const float* bhh1 = (const float*)d_in[8];
  const float* fc1w = (const float*)d_in[9];
  const float* fc1b = (const float*)d_in[10];
  const float* fc2w = (const float*)d_in[11];
  const float* fc2b = (const float*)d_in[12];
  lstm2_fused<<<dim3(1024), dim3(256), 0, stream>>>(
      x, Wih0, Whh0, bih0, bhh0, Wih1, Whh1, bih1, bhh1,
      fc1w, fc1b, fc2w, fc2b, (float*)d_out);
}

// Round 2
// 459.194 us; speedup vs baseline: 1.1224x; 1.1224x over previous
//
#include <hip/hip_runtime.h>
#include <stdint.h>

#define T_STEPS 512
#define D_INP   32
#define CHUNK   8
#define NCHUNK  (T_STEPS / CHUNK)

typedef float f2 __attribute__((ext_vector_type(2)));
typedef float f4 __attribute__((ext_vector_type(4)));

typedef const uint32_t __attribute__((address_space(1)))* gas1_t;
typedef uint32_t __attribute__((address_space(3)))* las3_t;

#define LOG2E 1.44269504088896f
#define TANHK (-2.88539008177793f)   // -2*log2(e)

template <int K>
__device__ __forceinline__ float qbcast(float v) {
  // broadcast lane (quad_base + K) to all 4 lanes of each quad (VALU pipe)
  return __int_as_float(
      __builtin_amdgcn_mov_dpp(__float_as_int(v), K * 85, 0xF, 0xF, true));
}

__device__ __forceinline__ float frcp(float v) { return __builtin_amdgcn_rcpf(v); }
__device__ __forceinline__ float fexp2(float v) { return __builtin_amdgcn_exp2f(v); }
__device__ __forceinline__ f2 lo2(f4 v) { return __builtin_shufflevector(v, v, 0, 1); }
__device__ __forceinline__ f2 hi2(f4 v) { return __builtin_shufflevector(v, v, 2, 3); }
__device__ __forceinline__ f2 pkfma(f2 a, f2 b, f2 c) {
  return __builtin_elementwise_fma(a, b, c);   // v_pk_fma_f32 on gfx90a+
}

extern "C" __global__ void __launch_bounds__(256, 4)
lstm2_fused(const float* __restrict__ x,
            const float* __restrict__ Wih0, const float* __restrict__ Whh0,
            const float* __restrict__ bih0, const float* __restrict__ bhh0,
            const float* __restrict__ Wih1, const float* __restrict__ Whh1,
            const float* __restrict__ bih1, const float* __restrict__ bhh1,
            const float* __restrict__ fc1w, const float* __restrict__ fc1b,
            const float* __restrict__ fc2w, const float* __restrict__ fc2b,
            float* __restrict__ out)
{
  __shared__ __align__(16) float lx[4][2][CHUNK * D_INP]; // 8KB: x staging, dbuf
  __shared__ __align__(16) float lh0[4][80];              // [0:16) h0, [16:80) dump
  __shared__ __align__(16) float lh1[4][80];

  const int tid  = threadIdx.x;
  const int w    = tid >> 6;
  const int lane = tid & 63;
  const int b    = (blockIdx.x << 2) + w;

  const int k   = lane & 3;      // gate type: 0=i 1=f 2=g(tanh) 3=o
  const int u   = lane >> 2;     // hidden unit 0..15
  const int row = k * 16 + u;    // weight row in the 64-gate matrices

  // prescale: gs' = sc * (W.x + b)  so activation uses exp2 directly.
  // sigma lanes: sc=-log2e -> exp2(gs')=exp(-z); g lane: sc=-2log2e -> exp(-2z)
  const float sc = (k == 2) ? -2.0f * LOG2E : -LOG2E;
  const float mA = (k == 2) ?  2.0f : 1.0f;
  const float aA = (k == 2) ? -1.0f : 0.0f;

  // ---- per-lane weights in VGPRs (prescaled, as f2 pairs) ----
  f2 wi0[16], wh0[8], wi1[8], wh1[8];
  {
    const f4* p = (const f4*)(Wih0 + row * 32);
#pragma unroll
    for (int q = 0; q < 8; ++q) {
      f4 v = p[q];
      wi0[2 * q + 0] = lo2(v) * sc;
      wi0[2 * q + 1] = hi2(v) * sc;
    }
    const f4* p0 = (const f4*)(Whh0 + row * 16);
    const f4* p1 = (const f4*)(Wih1 + row * 16);
    const f4* p2 = (const f4*)(Whh1 + row * 16);
#pragma unroll
    for (int q = 0; q < 4; ++q) {
      f4 a = p0[q], bq = p1[q], cq = p2[q];
      wh0[2 * q] = lo2(a) * sc;  wh0[2 * q + 1] = hi2(a) * sc;
      wi1[2 * q] = lo2(bq) * sc; wi1[2 * q + 1] = hi2(bq) * sc;
      wh1[2 * q] = lo2(cq) * sc; wh1[2 * q + 1] = hi2(cq) * sc;
    }
  }
  const float bs0 = sc * (bih0[row] + bhh0[row]);
  const float bs1 = sc * (bih1[row] + bhh1[row]);

  // branchless compact h write: k==0 lanes land in [0:16), others in dump zone
  const int slot = (k == 0) ? u : (16 + lane);
  float* h0slot = &lh0[w][slot];
  float* h1slot = &lh1[w][slot];

  float c0 = 0.f, c1 = 0.f;
  f2 h0p[8];
#pragma unroll
  for (int j = 0; j < 8; ++j) h0p[j] = (f2){0.f, 0.f};
  if (lane < 16) lh1[w][lane] = 0.f;  // h1[t=-1] = 0 (read before first write)

  const float* xg = x + (size_t)b * (T_STEPS * D_INP);

  // stage chunk 0 (1KB contiguous: 64 lanes x 16B)
  {
    const float* src = xg + lane * 4;
    __builtin_amdgcn_global_load_lds((gas1_t)(const void*)src,
                                     (las3_t)(void*)&lx[w][0][0], 16, 0, 0);
  }

#pragma unroll 1
  for (int c = 0; c < NCHUNK; ++c) {
    asm volatile("s_waitcnt vmcnt(0)" ::: "memory");
    if (c + 1 < NCHUNK) {
      const float* src = xg + (c + 1) * (CHUNK * D_INP) + lane * 4;
      __builtin_amdgcn_global_load_lds((gas1_t)(const void*)src,
                                       (las3_t)(void*)&lx[w][(c + 1) & 1][0],
                                       16, 0, 0);
    }
    const float* xp = &lx[w][c & 1][0];
#pragma unroll
    for (int tt = 0; tt < CHUNK; ++tt) {
      const float* xq = xp + tt * D_INP;
      // hoist h1[t-1] broadcast reads: long latency slack under layer-0 math
      f4 hA = *(const f4*)(&lh1[w][0]);
      f4 hB = *(const f4*)(&lh1[w][4]);
      f4 hC = *(const f4*)(&lh1[w][8]);
      f4 hD = *(const f4*)(&lh1[w][12]);
      // ======== layer 0 ========
      f2 a01 = (f2){bs0, 0.f}, a23 = (f2){0.f, 0.f};
#pragma unroll
      for (int q = 0; q < 8; ++q) {
        f4 v = *(const f4*)(xq + 4 * q);   // ds_read_b128 broadcast
        a01 = pkfma(wi0[2 * q + 0], lo2(v), a01);
        a23 = pkfma(wi0[2 * q + 1], hi2(v), a23);
      }
#pragma unroll
      for (int q = 0; q < 4; ++q) {
        a01 = pkfma(wh0[2 * q + 0], h0p[2 * q + 0], a01);
        a23 = pkfma(wh0[2 * q + 1], h0p[2 * q + 1], a23);
      }
      f2 asum = a01 + a23;                 // v_pk_add_f32
      float gs = asum.x + asum.y;
      float av = fmaf(mA, frcp(1.f + fexp2(gs)), aA);
      float iv = qbcast<0>(av), fv = qbcast<1>(av);
      float gv = qbcast<2>(av), ov = qbcast<3>(av);
      c0 = fmaf(fv, c0, iv * gv);
      float th = fmaf(2.f, frcp(1.f + fexp2(TANHK * c0)), -1.f);
      float h0n = ov * th;
      *h0slot = h0n;                        // compact write of h0[t]
#pragma unroll
      for (int q = 0; q < 4; ++q) {         // broadcast h0[t]; reused for Whh0(t+1)
        f4 hv = *(const f4*)(&lh0[w][4 * q]);
        h0p[2 * q + 0] = lo2(hv);
        h0p[2 * q + 1] = hi2(hv);
      }
      // ======== layer 1 ========
      f2 b01 = (f2){bs1, 0.f}, b23 = (f2){0.f, 0.f};
#pragma unroll
      for (int q = 0; q < 4; ++q) {
        b01 = pkfma(wi1[2 * q + 0], h0p[2 * q + 0], b01);
        b23 = pkfma(wi1[2 * q + 1], h0p[2 * q + 1], b23);
      }
      b01 = pkfma(wh1[0], lo2(hA), b01);  b23 = pkfma(wh1[1], hi2(hA), b23);
      b01 = pkfma(wh1[2], lo2(hB), b01);  b23 = pkfma(wh1[3], hi2(hB), b23);
      b01 = pkfma(wh1[4], lo2(hC), b01);  b23 = pkfma(wh1[5], hi2(hC), b23);
      b01 = pkfma(wh1[6], lo2(hD), b01);  b23 = pkfma(wh1[7], hi2(hD), b23);
      f2 bsum = b01 + b23;
      float gs1 = bsum.x + bsum.y;
      float av1 = fmaf(mA, frcp(1.f + fexp2(gs1)), aA);
      float iv1 = qbcast<0>(av1), fv1 = qbcast<1>(av1);
      float gv1 = qbcast<2>(av1), ov1 = qbcast<3>(av1);
      c1 = fmaf(fv1, c1, iv1 * gv1);
      float th1 = fmaf(2.f, frcp(1.f + fexp2(TANHK * c1)), -1.f);
      float h1n = ov1 * th1;
      *h1slot = h1n;                        // h1[t] for next step
    }
  }

  // ======== head: y = relu(h1_T @ fc1^T + b1) @ fc2^T + b2 ========
  float h1f[16];
#pragma unroll
  for (int q = 0; q < 4; ++q) {
    f4 hv = *(const f4*)(&lh1[w][4 * q]);
#pragma unroll
    for (int r = 0; r < 4; ++r) h1f[4 * q + r] = hv[r];
  }
  float rr = 0.f;
  if (lane < 8) {
    float acc = fc1b[lane];
#pragma unroll
    for (int j = 0; j < 16; ++j) acc = fmaf(fc1w[lane * 16 + j], h1f[j], acc);
    rr = fmaxf(acc, 0.f) * fc2w[lane];
  }
  rr += __shfl_xor(rr, 1, 64);
  rr += __shfl_xor(rr, 2, 64);
  rr += __shfl_xor(rr, 4, 64);
  if (lane == 0) out[b] = rr + fc2b[0];
}

extern "C" void kernel_launch(void* const* d_in, const int* in_sizes, int n_in,
                              void* d_out, int out_size, void* d_ws, size_t ws_size,
                              hipStream_t stream) {
  (void)in_sizes; (void)n_in; (void)d_ws; (void)ws_size; (void)out_size;
  const float* x    = (const float*)d_in[0];
  const float* Wih0 = (const float*)d_in[1];
  const float* Whh0 = (const float*)d_in[2];
  const float* bih0 = (const float*)d_in[3];
  const float* bhh0 = (const float*)d_in[4];
  const float* Wih1 = (const float*)d_in[5];
  const float* Whh1 = (const float*)d_in[6];
  const float* bih1 = (const float*)d_in[7];
  const float* bhh1 = (const float*)d_in[8];
  const float* fc1w = (const float*)d_in[9];
  const float* fc1b = (const float*)d_in[10];
  const float* fc2w = (const float*)d_in[11];
  const float* fc2b = (const float*)d_in[12];
  lstm2_fused<<<dim3(1024), dim3(256), 0, stream>>>(
      x, Wih0, Whh0, bih0, bhh0, Wih1, Whh1, bih1, bhh1,
      fc1w, fc1b, fc2w, fc2b, (float*)d_out);
}

// Round 3
// 408.670 us; speedup vs baseline: 1.2612x; 1.1236x over previous
//
#include <hip/hip_runtime.h>
#include <stdint.h>

#define T_STEPS 512
#define D_INP   32
#define CHUNK   8
#define NCHUNK  (T_STEPS / CHUNK)

typedef float f2 __attribute__((ext_vector_type(2)));
typedef float f4 __attribute__((ext_vector_type(4)));

typedef const uint32_t __attribute__((address_space(1)))* gas1_t;
typedef uint32_t __attribute__((address_space(3)))* las3_t;

#define LOG2E 1.44269504088896f
#define TANHK (-2.88539008177793f)   // -2*log2(e)

template <int K>
__device__ __forceinline__ float qbcast(float v) {
  // broadcast lane (quad_base + K) to all 4 lanes of each quad (VALU pipe)
  return __int_as_float(
      __builtin_amdgcn_mov_dpp(__float_as_int(v), K * 85, 0xF, 0xF, true));
}

__device__ __forceinline__ float frcp(float v) { return __builtin_amdgcn_rcpf(v); }
__device__ __forceinline__ float fexp2(float v) { return __builtin_amdgcn_exp2f(v); }
__device__ __forceinline__ f2 lo2(f4 v) { return __builtin_shufflevector(v, v, 0, 1); }
__device__ __forceinline__ f2 hi2(f4 v) { return __builtin_shufflevector(v, v, 2, 3); }
__device__ __forceinline__ f2 pkfma(f2 a, f2 b, f2 c) {
  return __builtin_elementwise_fma(a, b, c);   // v_pk_fma_f32
}

extern "C" __global__ void __launch_bounds__(256)
lstm2_fused(const float* __restrict__ x,
            const float* __restrict__ Wih0, const float* __restrict__ Whh0,
            const float* __restrict__ bih0, const float* __restrict__ bhh0,
            const float* __restrict__ Wih1, const float* __restrict__ Whh1,
            const float* __restrict__ bih1, const float* __restrict__ bhh1,
            const float* __restrict__ fc1w, const float* __restrict__ fc1b,
            const float* __restrict__ fc2w, const float* __restrict__ fc2b,
            float* __restrict__ out)
{
  __shared__ __align__(16) float lx[4][2][CHUNK * D_INP]; // 8KB: x staging, dbuf
  __shared__ __align__(16) float lh0[4][80];              // [0:16) h0, [16:80) dump
  __shared__ __align__(16) float lh1[4][80];

  const int tid  = threadIdx.x;
  const int w    = tid >> 6;
  const int lane = tid & 63;
  const int b    = (blockIdx.x << 2) + w;

  const int k   = lane & 3;      // gate type: 0=i 1=f 2=g(tanh) 3=o
  const int u   = lane >> 2;     // hidden unit 0..15
  const int row = k * 16 + u;    // weight row in the 64-gate matrices

  // prescale: gs' = sc * (W.x + b)  so activation uses exp2 directly.
  const float sc = (k == 2) ? -2.0f * LOG2E : -LOG2E;
  const float mA = (k == 2) ?  2.0f : 1.0f;
  const float aA = (k == 2) ? -1.0f : 0.0f;

  // ---- per-lane weights in VGPRs (prescaled, as f2 pairs) ----
  f2 wi0[16], wh0[8], wi1[8], wh1[8];
  {
    const f4* p = (const f4*)(Wih0 + row * 32);
#pragma unroll
    for (int q = 0; q < 8; ++q) {
      f4 v = p[q];
      wi0[2 * q + 0] = lo2(v) * sc;
      wi0[2 * q + 1] = hi2(v) * sc;
    }
    const f4* p0 = (const f4*)(Whh0 + row * 16);
    const f4* p1 = (const f4*)(Wih1 + row * 16);
    const f4* p2 = (const f4*)(Whh1 + row * 16);
#pragma unroll
    for (int q = 0; q < 4; ++q) {
      f4 a = p0[q], bq = p1[q], cq = p2[q];
      wh0[2 * q] = lo2(a) * sc;  wh0[2 * q + 1] = hi2(a) * sc;
      wi1[2 * q] = lo2(bq) * sc; wi1[2 * q + 1] = hi2(bq) * sc;
      wh1[2 * q] = lo2(cq) * sc; wh1[2 * q + 1] = hi2(cq) * sc;
    }
  }
  const float bs0 = sc * (bih0[row] + bhh0[row]);
  const float bs1 = sc * (bih1[row] + bhh1[row]);

  // branchless compact h write: k==0 lanes land in [0:16), others in dump zone
  const int slot = (k == 0) ? u : (16 + lane);
  float* h0slot = &lh0[w][slot];
  float* h1slot = &lh1[w][slot];

  float c0 = 0.f, c1 = 0.f;
  f2 h0p[8];
#pragma unroll
  for (int j = 0; j < 8; ++j) h0p[j] = (f2){0.f, 0.f};
  if (lane < 16) lh1[w][lane] = 0.f;  // h1[t=-1] = 0 (read before first write)

  const float* xg = x + (size_t)b * (T_STEPS * D_INP);

  // stage chunk 0 (1KB contiguous: 64 lanes x 16B)
  {
    const float* src = xg + lane * 4;
    __builtin_amdgcn_global_load_lds((gas1_t)(const void*)src,
                                     (las3_t)(void*)&lx[w][0][0], 16, 0, 0);
  }

#pragma unroll 1
  for (int c = 0; c < NCHUNK; ++c) {
    asm volatile("s_waitcnt vmcnt(0)" ::: "memory");
    if (c + 1 < NCHUNK) {
      const float* src = xg + (c + 1) * (CHUNK * D_INP) + lane * 4;
      __builtin_amdgcn_global_load_lds((gas1_t)(const void*)src,
                                       (las3_t)(void*)&lx[w][(c + 1) & 1][0],
                                       16, 0, 0);
    }
    const float* xp = &lx[w][c & 1][0];
#pragma unroll
    for (int tt = 0; tt < CHUNK; ++tt) {
      const float* xq = xp + tt * D_INP;
      // hoist h1[t-1] broadcast reads + Whh1 partial: independent of h0[t]
      f4 hA = *(const f4*)(&lh1[w][0]);
      f4 hB = *(const f4*)(&lh1[w][4]);
      f4 hC = *(const f4*)(&lh1[w][8]);
      f4 hD = *(const f4*)(&lh1[w][12]);
      f2 b01 = (f2){bs1, 0.f}, b23 = (f2){0.f, 0.f};
      b01 = pkfma(wh1[0], lo2(hA), b01);  b23 = pkfma(wh1[1], hi2(hA), b23);
      b01 = pkfma(wh1[2], lo2(hB), b01);  b23 = pkfma(wh1[3], hi2(hB), b23);
      b01 = pkfma(wh1[4], lo2(hC), b01);  b23 = pkfma(wh1[5], hi2(hC), b23);
      b01 = pkfma(wh1[6], lo2(hD), b01);  b23 = pkfma(wh1[7], hi2(hD), b23);
      // ======== layer 0 ========
      f2 a01 = (f2){bs0, 0.f}, a23 = (f2){0.f, 0.f};
#pragma unroll
      for (int q = 0; q < 8; ++q) {
        f4 v = *(const f4*)(xq + 4 * q);   // ds_read_b128 broadcast
        a01 = pkfma(wi0[2 * q + 0], lo2(v), a01);
        a23 = pkfma(wi0[2 * q + 1], hi2(v), a23);
      }
#pragma unroll
      for (int q = 0; q < 4; ++q) {
        a01 = pkfma(wh0[2 * q + 0], h0p[2 * q + 0], a01);
        a23 = pkfma(wh0[2 * q + 1], h0p[2 * q + 1], a23);
      }
      f2 asum = a01 + a23;                 // v_pk_add_f32
      float gs = asum.x + asum.y;
      float av = fmaf(mA, frcp(1.f + fexp2(gs)), aA);
      // iv := own av (correct on the k==0 lanes, the only ones whose h lands)
      float fv = qbcast<1>(av), gv = qbcast<2>(av), ov = qbcast<3>(av);
      c0 = fmaf(fv, c0, av * gv);
      float th = fmaf(2.f, frcp(1.f + fexp2(TANHK * c0)), -1.f);
      float h0n = ov * th;
      *h0slot = h0n;                        // compact write of h0[t]
#pragma unroll
      for (int q = 0; q < 4; ++q) {         // broadcast h0[t]; reused for Whh0(t+1)
        f4 hv = *(const f4*)(&lh0[w][4 * q]);
        h0p[2 * q + 0] = lo2(hv);
        h0p[2 * q + 1] = hi2(hv);
      }
      // ======== layer 1 (tail: only Wih1·h0[t] after the LDS read) ========
#pragma unroll
      for (int q = 0; q < 4; ++q) {
        b01 = pkfma(wi1[2 * q + 0], h0p[2 * q + 0], b01);
        b23 = pkfma(wi1[2 * q + 1], h0p[2 * q + 1], b23);
      }
      f2 bsum = b01 + b23;
      float gs1 = bsum.x + bsum.y;
      float av1 = fmaf(mA, frcp(1.f + fexp2(gs1)), aA);
      float fv1 = qbcast<1>(av1), gv1 = qbcast<2>(av1), ov1 = qbcast<3>(av1);
      c1 = fmaf(fv1, c1, av1 * gv1);
      float th1 = fmaf(2.f, frcp(1.f + fexp2(TANHK * c1)), -1.f);
      float h1n = ov1 * th1;
      *h1slot = h1n;                        // h1[t] for next step
    }
  }

  // ======== head: y = relu(h1_T @ fc1^T + b1) @ fc2^T + b2 ========
  float h1f[16];
#pragma unroll
  for (int q = 0; q < 4; ++q) {
    f4 hv = *(const f4*)(&lh1[w][4 * q]);
#pragma unroll
    for (int r = 0; r < 4; ++r) h1f[4 * q + r] = hv[r];
  }
  float rr = 0.f;
  if (lane < 8) {
    float acc = fc1b[lane];
#pragma unroll
    for (int j = 0; j < 16; ++j) acc = fmaf(fc1w[lane * 16 + j], h1f[j], acc);
    rr = fmaxf(acc, 0.f) * fc2w[lane];
  }
  rr += __shfl_xor(rr, 1, 64);
  rr += __shfl_xor(rr, 2, 64);
  rr += __shfl_xor(rr, 4, 64);
  if (lane == 0) out[b] = rr + fc2b[0];
}

extern "C" void kernel_launch(void* const* d_in, const int* in_sizes, int n_in,
                              void* d_out, int out_size, void* d_ws, size_t ws_size,
                              hipStream_t stream) {
  (void)in_sizes; (void)n_in; (void)d_ws; (void)ws_size; (void)out_size;
  const float* x    = (const float*)d_in[0];
  const float* Wih0 = (const float*)d_in[1];
  const float* Whh0 = (const float*)d_in[2];
  const float* bih0 = (const float*)d_in[3];
  const float* bhh0 = (const float*)d_in[4];
  const float* Wih1 = (const float*)d_in[5];
  const float* Whh1 = (const float*)d_in[6];
  const float* bih1 = (const float*)d_in[7];
  const float* bhh1 = (const float*)d_in[8];
  const float* fc1w = (const float*)d_in[9];
  const float* fc1b = (const float*)d_in[10];
  const float* fc2w = (const float*)d_in[11];
  const float* fc2b = (const float*)d_in[12];
  lstm2_fused<<<dim3(1024), dim3(256), 0, stream>>>(
      x, Wih0, Whh0, bih0, bhh0, Wih1, Whh1, bih1, bhh1,
      fc1w, fc1b, fc2w, fc2b, (float*)d_out);
}